// Round 4
// baseline (1327.808 us; speedup 1.0000x reference)
//
#include <hip/hip_runtime.h>

typedef unsigned int uint;
typedef unsigned short ushort;
typedef __attribute__((ext_vector_type(8))) short bhalf8;
typedef __attribute__((ext_vector_type(4))) float floatx4;

#define D_IN 256
#define HSZ 512
#define GATESN 2048
#define NSUP 512
#define BATCH_N 32768
#define KCAT 768
#define LDA_A 1024   // A_cat layout: [h_a(0:256) | r(256:512) | q(512:768) | h_b(768:1024)]

__device__ __forceinline__ ushort f2b(float f){
  union { float f; uint u; } x; x.f = f;
  uint r = (x.u + 0x7fffu + ((x.u >> 16) & 1u)) >> 16;
  return (ushort)r;
}
__device__ __forceinline__ float b2f(ushort u){
  union { uint u; float f; } x; x.u = ((uint)u) << 16;
  return x.f;
}
__device__ __forceinline__ float sigmf(float x){ return 1.0f / (1.0f + __expf(-x)); }
__device__ __forceinline__ float tanhfast(float x){ return 1.0f - 2.0f / (1.0f + __expf(2.0f * x)); }

// global->LDS direct staging of a 128x64 bf16 tile.
// Linear LDS [128][64]; wave w stages rows [32w+8q, 32w+8q+8), lane i lands at
// base + i*16B = row (i>>3), col-octet (i&7)  (dest is wave-uniform base + lane*16).
__device__ __forceinline__ void stage_tile(
    ushort* lds, const ushort* g, int ld, int row0, int k0, int wave, int lane)
{
  #pragma unroll
  for (int q = 0; q < 4; q++) {
    const ushort* gp = g + (long)(row0 + wave * 32 + q * 8 + (lane >> 3)) * ld
                         + k0 + ((lane & 7) << 3);
    ushort* lp = lds + (wave * 32 + q * 8) * 64;
    __builtin_amdgcn_global_load_lds(
        (const __attribute__((address_space(1))) void*)gp,
        (__attribute__((address_space(3))) void*)lp, 16, 0, 0);
  }
}

// ---------------------------------------------------------------------------
// Fused gates GEMM + LSTM pointwise.
// gates = A_cat[:, aoff:aoff+768] @ Wperm^T  (128x128 tile, BK=64, gload_lds)
// W rows permuted so each 64-col slice = 16 units x 4 gates stride-16 =>
// acc[m][0..3] of a lane are (i,f,g,o) of ONE unit. Epilogue does the cell
// update in fp32 registers: c = f*c + i*g ; h = q + o*tanh(c) -> hi/lo bf16.
// ---------------------------------------------------------------------------
__global__ __launch_bounds__(256) void gemm_gates_fused(
    const ushort* __restrict__ A,      // Abuf + aoff (lda 1024)
    const ushort* __restrict__ W,      // permuted [2048,768]
    const float4* __restrict__ biasp,  // [512] = (b_i, b_f, b_g, b_o) per unit
    float* __restrict__ cbuf,          // [32768,512] fp32
    const float* __restrict__ query,   // [32768,256] fp32
    ushort* __restrict__ Hhi,          // Abuf + houtoff (stride 1024)
    ushort* __restrict__ Hlo)          // [32768,256]
{
  __shared__ ushort As[128 * 64];
  __shared__ ushort Bs[128 * 64];

  const int tid  = threadIdx.x;
  const int lane = tid & 63;
  const int wave = tid >> 6;
  const int wr = (wave >> 1) * 64;
  const int wc = (wave & 1) * 64;
  const int bm = blockIdx.x >> 4;     // GATESN/128 = 16 col-blocks
  const int bn = blockIdx.x & 15;
  const int rowA0 = bm * 128;
  const int colB0 = bn * 128;

  floatx4 acc[4][4];
  #pragma unroll
  for (int m = 0; m < 4; m++)
    #pragma unroll
    for (int n = 0; n < 4; n++)
      acc[m][n] = (floatx4){0.f, 0.f, 0.f, 0.f};

  const int lr = lane & 15;
  const int lk = (lane >> 4) << 3;

  for (int k0 = 0; k0 < KCAT; k0 += 64) {
    stage_tile(As, A, LDA_A, rowA0, k0, wave, lane);
    stage_tile(Bs, W, KCAT,  colB0, k0, wave, lane);
    __syncthreads();
    #pragma unroll
    for (int ks = 0; ks < 2; ks++) {
      bhalf8 af[4], bfr[4];
      #pragma unroll
      for (int m = 0; m < 4; m++)
        af[m] = *reinterpret_cast<const bhalf8*>(&As[(wr + m * 16 + lr) * 64 + ks * 32 + lk]);
      #pragma unroll
      for (int n = 0; n < 4; n++)
        bfr[n] = *reinterpret_cast<const bhalf8*>(&Bs[(wc + n * 16 + lr) * 64 + ks * 32 + lk]);
      #pragma unroll
      for (int m = 0; m < 4; m++)
        #pragma unroll
        for (int n = 0; n < 4; n++)
          acc[m][n] = __builtin_amdgcn_mfma_f32_16x16x32_bf16(af[m], bfr[n], acc[m][n], 0, 0, 0);
    }
    __syncthreads();
  }

  // ---- fused LSTM epilogue ----
  const int u = (2 * bn + (wc >> 6)) * 16 + lr;   // hidden unit, wave-uniform base
  const float4 b4 = biasp[u];
  const int lg = lane >> 4;
  #pragma unroll
  for (int m = 0; m < 4; m++) {
    #pragma unroll
    for (int rr = 0; rr < 4; rr++) {
      const long row = rowA0 + wr + m * 16 + lg * 4 + rr;
      float gi = sigmf(acc[m][0][rr] + b4.x);
      float gf = sigmf(acc[m][1][rr] + b4.y);
      float gg = tanhfast(acc[m][2][rr] + b4.z);
      float go = sigmf(acc[m][3][rr] + b4.w);
      float* cp = cbuf + row * HSZ + u;
      float cn = gf * (*cp) + gi * gg;
      *cp = cn;
      if (u < D_IN) {
        float h = query[row * D_IN + u] + go * tanhfast(cn);
        ushort hh = f2b(h);
        Hhi[row * LDA_A + u] = hh;
        Hlo[row * D_IN + u] = f2b(h - b2f(hh));
      }
    }
  }
}

// ---------------------------------------------------------------------------
// Split-precision scores GEMM: C = (Ahi+Alo) @ (Bhi+Blo)^T, dropping lo*lo.
// 128x128 tile, K=256, gload_lds staging. C fp32 [32768,512].
// ---------------------------------------------------------------------------
__global__ __launch_bounds__(256) void gemm_scores(
    const ushort* __restrict__ Ahi, int ldah,
    const ushort* __restrict__ Alo,
    const ushort* __restrict__ Bhi, const ushort* __restrict__ Blo,
    float* __restrict__ C)
{
  __shared__ ushort AsH[128 * 64];
  __shared__ ushort AsL[128 * 64];
  __shared__ ushort BsH[128 * 64];
  __shared__ ushort BsL[128 * 64];

  const int tid  = threadIdx.x;
  const int lane = tid & 63;
  const int wave = tid >> 6;
  const int wr = (wave >> 1) * 64;
  const int wc = (wave & 1) * 64;
  const int bm = blockIdx.x >> 2;      // NSUP/128 = 4
  const int bn = blockIdx.x & 3;
  const int rowA0 = bm * 128;
  const int rowB0 = bn * 128;

  floatx4 acc[4][4];
  #pragma unroll
  for (int m = 0; m < 4; m++)
    #pragma unroll
    for (int n = 0; n < 4; n++)
      acc[m][n] = (floatx4){0.f, 0.f, 0.f, 0.f};

  const int lr = lane & 15;
  const int lk = (lane >> 4) << 3;

  for (int k0 = 0; k0 < D_IN; k0 += 64) {
    stage_tile(AsH, Ahi, ldah, rowA0, k0, wave, lane);
    stage_tile(AsL, Alo, D_IN, rowA0, k0, wave, lane);
    stage_tile(BsH, Bhi, D_IN, rowB0, k0, wave, lane);
    stage_tile(BsL, Blo, D_IN, rowB0, k0, wave, lane);
    __syncthreads();
    #pragma unroll
    for (int ks = 0; ks < 2; ks++) {
      bhalf8 afh[4], afl[4], bfh[4], bfl[4];
      #pragma unroll
      for (int m = 0; m < 4; m++) {
        afh[m] = *reinterpret_cast<const bhalf8*>(&AsH[(wr + m * 16 + lr) * 64 + ks * 32 + lk]);
        afl[m] = *reinterpret_cast<const bhalf8*>(&AsL[(wr + m * 16 + lr) * 64 + ks * 32 + lk]);
      }
      #pragma unroll
      for (int n = 0; n < 4; n++) {
        bfh[n] = *reinterpret_cast<const bhalf8*>(&BsH[(wc + n * 16 + lr) * 64 + ks * 32 + lk]);
        bfl[n] = *reinterpret_cast<const bhalf8*>(&BsL[(wc + n * 16 + lr) * 64 + ks * 32 + lk]);
      }
      #pragma unroll
      for (int m = 0; m < 4; m++)
        #pragma unroll
        for (int n = 0; n < 4; n++) {
          acc[m][n] = __builtin_amdgcn_mfma_f32_16x16x32_bf16(afl[m], bfh[n], acc[m][n], 0, 0, 0);
          acc[m][n] = __builtin_amdgcn_mfma_f32_16x16x32_bf16(afh[m], bfl[n], acc[m][n], 0, 0, 0);
          acc[m][n] = __builtin_amdgcn_mfma_f32_16x16x32_bf16(afh[m], bfh[n], acc[m][n], 0, 0, 0);
        }
    }
    __syncthreads();
  }

  const int lg = lane >> 4;
  #pragma unroll
  for (int m = 0; m < 4; m++)
    #pragma unroll
    for (int n = 0; n < 4; n++)
      #pragma unroll
      for (int r = 0; r < 4; r++) {
        int row = rowA0 + wr + m * 16 + lg * 4 + r;
        int col = rowB0 + wc + n * 16 + lr;
        C[(long)row * NSUP + col] = acc[m][n][r];
      }
}

// ---------------------------------------------------------------------------
// Generic C = A*B^T (PV GEMM), gload_lds staging, bf16 out.
// ---------------------------------------------------------------------------
__global__ __launch_bounds__(256) void gemm_bt(
    const ushort* __restrict__ A, int lda,
    const ushort* __restrict__ B, int ldb,
    ushort* __restrict__ Cv, int ldc,
    int K, int nbn)
{
  __shared__ ushort As[128 * 64];
  __shared__ ushort Bs[128 * 64];

  const int tid  = threadIdx.x;
  const int lane = tid & 63;
  const int wave = tid >> 6;
  const int wr = (wave >> 1) * 64;
  const int wc = (wave & 1) * 64;
  const int bm = blockIdx.x / nbn;
  const int bn = blockIdx.x % nbn;
  const int rowA0 = bm * 128;
  const int rowB0 = bn * 128;

  floatx4 acc[4][4];
  #pragma unroll
  for (int m = 0; m < 4; m++)
    #pragma unroll
    for (int n = 0; n < 4; n++)
      acc[m][n] = (floatx4){0.f, 0.f, 0.f, 0.f};

  const int lr = lane & 15;
  const int lk = (lane >> 4) << 3;

  for (int k0 = 0; k0 < K; k0 += 64) {
    stage_tile(As, A, lda, rowA0, k0, wave, lane);
    stage_tile(Bs, B, ldb, rowB0, k0, wave, lane);
    __syncthreads();
    #pragma unroll
    for (int ks = 0; ks < 2; ks++) {
      bhalf8 af[4], bfr[4];
      #pragma unroll
      for (int m = 0; m < 4; m++)
        af[m] = *reinterpret_cast<const bhalf8*>(&As[(wr + m * 16 + lr) * 64 + ks * 32 + lk]);
      #pragma unroll
      for (int n = 0; n < 4; n++)
        bfr[n] = *reinterpret_cast<const bhalf8*>(&Bs[(wc + n * 16 + lr) * 64 + ks * 32 + lk]);
      #pragma unroll
      for (int m = 0; m < 4; m++)
        #pragma unroll
        for (int n = 0; n < 4; n++)
          acc[m][n] = __builtin_amdgcn_mfma_f32_16x16x32_bf16(af[m], bfr[n], acc[m][n], 0, 0, 0);
    }
    __syncthreads();
  }

  const int lg = lane >> 4;
  #pragma unroll
  for (int m = 0; m < 4; m++)
    #pragma unroll
    for (int n = 0; n < 4; n++)
      #pragma unroll
      for (int r = 0; r < 4; r++) {
        int row = rowA0 + wr + m * 16 + lg * 4 + r;
        int col = rowB0 + wc + n * 16 + lr;
        Cv[(long)row * ldc + col] = f2b(acc[m][n][r]);
      }
}

// ---------------------------------------------------------------------------
// Build permuted weights (even/odd K-order), packed bias, S hi/lo, S^T.
// Permuted col c: unit = (c>>6)*16 + (c&15), gate = (c>>4)&3.
// even K-order: [Whh_h | Whh_r | Wih] ; odd: [Whh_r | Wih | Whh_h]
// ---------------------------------------------------------------------------
__global__ __launch_bounds__(256) void k_build(
    const float* __restrict__ Wih, const float* __restrict__ Whh,
    const float* __restrict__ bih, const float* __restrict__ bhh,
    const float* __restrict__ S,
    ushort* __restrict__ We, ushort* __restrict__ Wo,
    float4* __restrict__ biasp,
    ushort* __restrict__ Shi, ushort* __restrict__ Slo,
    ushort* __restrict__ STb)
{
  int t = blockIdx.x * 256 + threadIdx.x;
  if (t < GATESN * KCAT) {
    int c = t / KCAT, k = t % KCAT;
    int unit = (c >> 6) * 16 + (c & 15);
    int gate = (c >> 4) & 3;
    long srow = (long)(gate * HSZ + unit);
    float ve = (k < HSZ) ? Whh[srow * HSZ + k] : Wih[srow * D_IN + (k - HSZ)];
    float vo;
    if (k < D_IN)           vo = Whh[srow * HSZ + D_IN + k];   // r part
    else if (k < HSZ)       vo = Wih[srow * D_IN + (k - D_IN)]; // q part
    else                    vo = Whh[srow * HSZ + (k - HSZ)];   // h part
    We[(long)c * KCAT + k] = f2b(ve);
    Wo[(long)c * KCAT + k] = f2b(vo);
  }
  if (t < HSZ) {
    biasp[t] = make_float4(bih[t] + bhh[t],
                           bih[HSZ + t] + bhh[HSZ + t],
                           bih[2 * HSZ + t] + bhh[2 * HSZ + t],
                           bih[3 * HSZ + t] + bhh[3 * HSZ + t]);
  }
  if (t < NSUP * D_IN) {
    float v = S[t];
    ushort hv = f2b(v);
    Shi[t] = hv;
    Slo[t] = f2b(v - b2f(hv));
    int s = t >> 8, d = t & 255;
    STb[(long)d * NSUP + s] = hv;
  }
}

// A_cat init: q into cols 512:768, zeros elsewhere; c = 0.
__global__ __launch_bounds__(256) void k_initA(
    const float* __restrict__ query, ushort* __restrict__ Abuf, float* __restrict__ c)
{
  long t = (long)blockIdx.x * 256 + threadIdx.x;
  const long nA = (long)BATCH_N * LDA_A;
  if (t < nA) {
    int b = (int)(t >> 10), col = (int)(t & 1023);
    Abuf[t] = (col >= 512 && col < 768) ? f2b(query[(long)b * D_IN + (col - 512)]) : (ushort)0;
  } else {
    c[t - nA] = 0.f;
  }
}

// Row softmax over 512 cols, fp32 in, bf16 out. 1 wave / row.
__global__ __launch_bounds__(256) void k_softmax(
    const float* __restrict__ sc, ushort* __restrict__ attn)
{
  int row  = blockIdx.x * 4 + (threadIdx.x >> 6);
  int lane = threadIdx.x & 63;
  const float4* sp = reinterpret_cast<const float4*>(sc + (long)row * NSUP);
  float4 v0 = sp[lane];
  float4 v1 = sp[64 + lane];
  float m = fmaxf(fmaxf(fmaxf(v0.x, v0.y), fmaxf(v0.z, v0.w)),
                  fmaxf(fmaxf(v1.x, v1.y), fmaxf(v1.z, v1.w)));
  #pragma unroll
  for (int off = 32; off >= 1; off >>= 1) m = fmaxf(m, __shfl_xor(m, off));
  float e0 = __expf(v0.x - m), e1 = __expf(v0.y - m), e2 = __expf(v0.z - m), e3 = __expf(v0.w - m);
  float e4 = __expf(v1.x - m), e5 = __expf(v1.y - m), e6 = __expf(v1.z - m), e7 = __expf(v1.w - m);
  float s = e0 + e1 + e2 + e3 + e4 + e5 + e6 + e7;
  #pragma unroll
  for (int off = 32; off >= 1; off >>= 1) s += __shfl_xor(s, off);
  float inv = 1.0f / s;
  uint2 p0, p1;
  p0.x = (uint)f2b(e0 * inv) | ((uint)f2b(e1 * inv) << 16);
  p0.y = (uint)f2b(e2 * inv) | ((uint)f2b(e3 * inv) << 16);
  p1.x = (uint)f2b(e4 * inv) | ((uint)f2b(e5 * inv) << 16);
  p1.y = (uint)f2b(e6 * inv) | ((uint)f2b(e7 * inv) << 16);
  uint2* ap = reinterpret_cast<uint2*>(attn + (long)row * NSUP);
  ap[lane] = p0;
  ap[64 + lane] = p1;
}

// ---------------------------------------------------------------------------
extern "C" void kernel_launch(void* const* d_in, const int* in_sizes, int n_in,
                              void* d_out, int out_size, void* d_ws, size_t ws_size,
                              hipStream_t stream)
{
  const float* support_mean = (const float*)d_in[0];
  const float* query_mean   = (const float*)d_in[2];
  const float* W_ih = (const float*)d_in[4];
  const float* W_hh = (const float*)d_in[5];
  const float* b_ih = (const float*)d_in[6];
  const float* b_hh = (const float*)d_in[7];
  float* out = (float*)d_out;

  char* ws = (char*)d_ws;
  size_t off = 0;
  auto alloc = [&](size_t bytes) {
    void* p = ws + off;
    off += (bytes + 255) & ~(size_t)255;
    return p;
  };
  ushort* Abuf  = (ushort*)alloc((size_t)BATCH_N * LDA_A * 2);  // 67.1 MB
  ushort* We    = (ushort*)alloc((size_t)GATESN * KCAT * 2);    // 3.1 MB
  ushort* Wo    = (ushort*)alloc((size_t)GATESN * KCAT * 2);    // 3.1 MB
  float4* biasp = (float4*)alloc((size_t)HSZ * 16);
  ushort* Shi   = (ushort*)alloc((size_t)NSUP * D_IN * 2);
  ushort* Slo   = (ushort*)alloc((size_t)NSUP * D_IN * 2);
  ushort* STb   = (ushort*)alloc((size_t)D_IN * NSUP * 2);
  float*  cbuf  = (float*) alloc((size_t)BATCH_N * HSZ * 4);    // 67.1 MB
  ushort* Hlo   = (ushort*)alloc((size_t)BATCH_N * D_IN * 2);   // 16.8 MB
  ushort* attn  = (ushort*)alloc((size_t)BATCH_N * NSUP * 2);   // 33.6 MB
  if (off > ws_size) return;  // total ~191 MB; >=255 MB proven available

  hipLaunchKernelGGL(k_build, dim3((GATESN * KCAT) / 256), dim3(256), 0, stream,
                     W_ih, W_hh, b_ih, b_hh, support_mean,
                     We, Wo, biasp, Shi, Slo, STb);
  hipLaunchKernelGGL(k_initA, dim3((BATCH_N * (LDA_A + HSZ)) / 256), dim3(256), 0, stream,
                     query_mean, Abuf, cbuf);

  for (int step = 0; step < 4; step++) {
    const int odd = step & 1;
    const int aoff = odd ? 256 : 0;     // K-window: even [h_a|r|q], odd [r|q|h_b]
    const int hout = odd ? 0 : 768;     // write h into the other buffer
    // fused gates GEMM + LSTM cell
    hipLaunchKernelGGL(gemm_gates_fused,
                       dim3((BATCH_N / 128) * (GATESN / 128)), dim3(256), 0, stream,
                       Abuf + aoff, odd ? Wo : We, biasp, cbuf, query_mean,
                       Abuf + hout, Hlo);
    // scores = h @ S^T (split precision) -> d_out fp32
    hipLaunchKernelGGL(gemm_scores,
                       dim3((BATCH_N / 128) * (NSUP / 128)), dim3(256), 0, stream,
                       Abuf + hout, LDA_A, Hlo, Shi, Slo, out);
    if (step < 3) {
      hipLaunchKernelGGL(k_softmax, dim3(BATCH_N / 4), dim3(256), 0, stream, out, attn);
      // r = attn @ S -> bf16 into A_cat[:,256:512]
      hipLaunchKernelGGL(gemm_bt,
                         dim3((BATCH_N / 128) * (D_IN / 128)), dim3(256), 0, stream,
                         attn, NSUP, STb, NSUP, Abuf + 256, LDA_A, NSUP, D_IN / 128);
    }
  }
}

// Round 5
// 964.928 us; speedup vs baseline: 1.3761x; 1.3761x over previous
//
#include <hip/hip_runtime.h>

typedef unsigned int uint;
typedef unsigned short ushort;
typedef __attribute__((ext_vector_type(8))) short bhalf8;
typedef __attribute__((ext_vector_type(4))) float floatx4;

#define D_IN 256
#define HSZ 512
#define GATESN 2048
#define NSUP 512
#define BATCH_N 32768
#define LDA_A 1024   // A_cat: [h_a(0:256) | r(256:512) | q(512:768) | h_b(768:1024)]

__device__ __forceinline__ ushort f2b(float f){
  union { float f; uint u; } x; x.f = f;
  uint r = (x.u + 0x7fffu + ((x.u >> 16) & 1u)) >> 16;
  return (ushort)r;
}
__device__ __forceinline__ float b2f(ushort u){
  union { uint u; float f; } x; x.u = ((uint)u) << 16;
  return x.f;
}
__device__ __forceinline__ float sigmf(float x){ return 1.0f / (1.0f + __expf(-x)); }
__device__ __forceinline__ float tanhfast(float x){ return 1.0f - 2.0f / (1.0f + __expf(2.0f * x)); }

// ---------------------------------------------------------------------------
// global->LDS staging of a 128x64 bf16 tile with SOURCE PRE-SWIZZLE (m173):
// LDS stays linear (gload_lds dest = wave base + lane*16B); lane fetches the
// global octet (lane&7)^(lane>>3), so LDS[R][o] = G[R][o ^ (R&7)].
// Reads must apply the same XOR (frag_ld). 128B source segments are permuted
// within themselves -> coalescing unchanged; ds_read becomes conflict-free.
// ---------------------------------------------------------------------------
__device__ __forceinline__ void stage_swz(
    ushort* lds, const ushort* __restrict__ g, int ld, int row0, int k0,
    int wave, int lane)
{
  const int rsub = lane >> 3;          // 0..7
  const int oct  = (lane & 7) ^ rsub;  // pre-swizzled source octet
  #pragma unroll
  for (int q = 0; q < 4; q++) {
    const ushort* gp = g + (long)(row0 + wave * 32 + q * 8 + rsub) * ld
                         + k0 + (oct << 3);
    ushort* lp = lds + (wave * 32 + q * 8) * 64;
    __builtin_amdgcn_global_load_lds(
        (const __attribute__((address_space(1))) void*)gp,
        (__attribute__((address_space(3))) void*)lp, 16, 0, 0);
  }
}

// Read G[R][octet O] from swizzled LDS; sx = lane&7 (= R&7 for R = base16+lr).
__device__ __forceinline__ bhalf8 frag_ld(const ushort* lds, int R, int O, int sx)
{
  return *reinterpret_cast<const bhalf8*>(&lds[R * 64 + (((O ^ sx) & 7) << 3)]);
}

// ---------------------------------------------------------------------------
// Fused gates GEMM + LSTM pointwise. gates = A[:,0:KLEN] @ W^T (permuted W:
// acc[m][0..3] of a lane = (i,f,g,o) of ONE unit). FIRST=1: c = i*g (no read).
// ---------------------------------------------------------------------------
template<int FIRST, int KLEN>
__global__ __launch_bounds__(256) void gemm_gates_fused(
    const ushort* __restrict__ A,      // lda = LDA_A
    const ushort* __restrict__ W,      // permuted [2048, KLEN]
    const float4* __restrict__ biasp,  // [512] = (b_i,b_f,b_g,b_o) per unit
    float* __restrict__ cbuf,          // [32768,512] fp32
    const float* __restrict__ query,   // [32768,256] fp32
    ushort* __restrict__ Hhi,          // A_cat h-out slot (stride LDA_A)
    ushort* __restrict__ Hlo)          // [32768,256]
{
  __shared__ ushort As[128 * 64];
  __shared__ ushort Bs[128 * 64];

  const int tid  = threadIdx.x;
  const int lane = tid & 63;
  const int wave = tid >> 6;
  const int wr = (wave >> 1) * 64;
  const int wc = (wave & 1) * 64;
  // bijective XCD swizzle (grid 4096 %8==0): contiguous wg chunk per XCD
  const int wg = (blockIdx.x & 7) * (gridDim.x >> 3) + (blockIdx.x >> 3);
  const int bm = wg >> 4;             // GATESN/128 = 16 col-blocks
  const int bn = wg & 15;
  const int rowA0 = bm * 128;
  const int colB0 = bn * 128;

  floatx4 acc[4][4];
  #pragma unroll
  for (int m = 0; m < 4; m++)
    #pragma unroll
    for (int n = 0; n < 4; n++)
      acc[m][n] = (floatx4){0.f, 0.f, 0.f, 0.f};

  const int lr = lane & 15;
  const int lg = lane >> 4;
  const int sx = lane & 7;

  for (int k0 = 0; k0 < KLEN; k0 += 64) {
    stage_swz(As, A, LDA_A, rowA0, k0, wave, lane);
    stage_swz(Bs, W, KLEN,  colB0, k0, wave, lane);
    __syncthreads();
    #pragma unroll
    for (int ks = 0; ks < 2; ks++) {
      bhalf8 af[4], bfr[4];
      #pragma unroll
      for (int m = 0; m < 4; m++)
        af[m] = frag_ld(As, wr + m * 16 + lr, ks * 4 + lg, sx);
      #pragma unroll
      for (int n = 0; n < 4; n++)
        bfr[n] = frag_ld(Bs, wc + n * 16 + lr, ks * 4 + lg, sx);
      #pragma unroll
      for (int m = 0; m < 4; m++)
        #pragma unroll
        for (int n = 0; n < 4; n++)
          acc[m][n] = __builtin_amdgcn_mfma_f32_16x16x32_bf16(af[m], bfr[n], acc[m][n], 0, 0, 0);
    }
    __syncthreads();
  }

  // ---- fused LSTM epilogue ----
  const int u = (2 * bn + (wave & 1)) * 16 + lr;   // hidden unit
  const float4 b4 = biasp[u];
  #pragma unroll
  for (int m = 0; m < 4; m++) {
    #pragma unroll
    for (int rr = 0; rr < 4; rr++) {
      const long row = rowA0 + wr + m * 16 + lg * 4 + rr;
      float gi = sigmf(acc[m][0][rr] + b4.x);
      float gf = sigmf(acc[m][1][rr] + b4.y);
      float gg = tanhfast(acc[m][2][rr] + b4.z);
      float go = sigmf(acc[m][3][rr] + b4.w);
      float* cp = cbuf + row * HSZ + u;
      float cn = FIRST ? (gi * gg) : (gf * (*cp) + gi * gg);
      *cp = cn;
      if (u < D_IN) {
        float h = query[row * D_IN + u] + go * tanhfast(cn);
        ushort hh = f2b(h);
        Hhi[row * LDA_A + u] = hh;
        Hlo[row * D_IN + u] = f2b(h - b2f(hh));
      }
    }
  }
}

// ---------------------------------------------------------------------------
// Split-precision scores GEMM: C = (Ahi+Alo) @ (Bhi+Blo)^T, dropping lo*lo.
// K=256. C fp32 [32768,512].
// ---------------------------------------------------------------------------
__global__ __launch_bounds__(256) void gemm_scores(
    const ushort* __restrict__ Ahi, int ldah,
    const ushort* __restrict__ Alo,
    const ushort* __restrict__ Bhi, const ushort* __restrict__ Blo,
    float* __restrict__ C)
{
  __shared__ ushort AsH[128 * 64];
  __shared__ ushort AsL[128 * 64];
  __shared__ ushort BsH[128 * 64];
  __shared__ ushort BsL[128 * 64];

  const int tid  = threadIdx.x;
  const int lane = tid & 63;
  const int wave = tid >> 6;
  const int wr = (wave >> 1) * 64;
  const int wc = (wave & 1) * 64;
  const int wg = (blockIdx.x & 7) * (gridDim.x >> 3) + (blockIdx.x >> 3);
  const int bm = wg >> 2;      // NSUP/128 = 4
  const int bn = wg & 3;
  const int rowA0 = bm * 128;
  const int rowB0 = bn * 128;

  floatx4 acc[4][4];
  #pragma unroll
  for (int m = 0; m < 4; m++)
    #pragma unroll
    for (int n = 0; n < 4; n++)
      acc[m][n] = (floatx4){0.f, 0.f, 0.f, 0.f};

  const int lr = lane & 15;
  const int lg = lane >> 4;
  const int sx = lane & 7;

  for (int k0 = 0; k0 < D_IN; k0 += 64) {
    stage_swz(AsH, Ahi, ldah, rowA0, k0, wave, lane);
    stage_swz(AsL, Alo, D_IN, rowA0, k0, wave, lane);
    stage_swz(BsH, Bhi, D_IN, rowB0, k0, wave, lane);
    stage_swz(BsL, Blo, D_IN, rowB0, k0, wave, lane);
    __syncthreads();
    #pragma unroll
    for (int ks = 0; ks < 2; ks++) {
      bhalf8 afh[4], afl[4], bfh[4], bfl[4];
      #pragma unroll
      for (int m = 0; m < 4; m++) {
        afh[m] = frag_ld(AsH, wr + m * 16 + lr, ks * 4 + lg, sx);
        afl[m] = frag_ld(AsL, wr + m * 16 + lr, ks * 4 + lg, sx);
      }
      #pragma unroll
      for (int n = 0; n < 4; n++) {
        bfh[n] = frag_ld(BsH, wc + n * 16 + lr, ks * 4 + lg, sx);
        bfl[n] = frag_ld(BsL, wc + n * 16 + lr, ks * 4 + lg, sx);
      }
      #pragma unroll
      for (int m = 0; m < 4; m++)
        #pragma unroll
        for (int n = 0; n < 4; n++) {
          acc[m][n] = __builtin_amdgcn_mfma_f32_16x16x32_bf16(afl[m], bfh[n], acc[m][n], 0, 0, 0);
          acc[m][n] = __builtin_amdgcn_mfma_f32_16x16x32_bf16(afh[m], bfl[n], acc[m][n], 0, 0, 0);
          acc[m][n] = __builtin_amdgcn_mfma_f32_16x16x32_bf16(afh[m], bfh[n], acc[m][n], 0, 0, 0);
        }
    }
    __syncthreads();
  }

  #pragma unroll
  for (int m = 0; m < 4; m++)
    #pragma unroll
    for (int n = 0; n < 4; n++)
      #pragma unroll
      for (int r = 0; r < 4; r++) {
        int row = rowA0 + wr + m * 16 + lg * 4 + r;
        int col = rowB0 + wc + n * 16 + lr;
        C[(long)row * NSUP + col] = acc[m][n][r];
      }
}

// ---------------------------------------------------------------------------
// PV GEMM: r = attn @ STb^T (K=512), bf16 out into A_cat r-slot.
// ---------------------------------------------------------------------------
__global__ __launch_bounds__(256) void gemm_pv(
    const ushort* __restrict__ A,      // attn [32768,512]
    const ushort* __restrict__ B,      // STb [256,512]
    ushort* __restrict__ Cv)           // Abuf + 256, ldc = LDA_A
{
  __shared__ ushort As[128 * 64];
  __shared__ ushort Bs[128 * 64];

  const int tid  = threadIdx.x;
  const int lane = tid & 63;
  const int wave = tid >> 6;
  const int wr = (wave >> 1) * 64;
  const int wc = (wave & 1) * 64;
  const int wg = (blockIdx.x & 7) * (gridDim.x >> 3) + (blockIdx.x >> 3);
  const int bm = wg >> 1;             // D_IN/128 = 2
  const int bn = wg & 1;
  const int rowA0 = bm * 128;
  const int rowB0 = bn * 128;

  floatx4 acc[4][4];
  #pragma unroll
  for (int m = 0; m < 4; m++)
    #pragma unroll
    for (int n = 0; n < 4; n++)
      acc[m][n] = (floatx4){0.f, 0.f, 0.f, 0.f};

  const int lr = lane & 15;
  const int lg = lane >> 4;
  const int sx = lane & 7;

  for (int k0 = 0; k0 < NSUP; k0 += 64) {
    stage_swz(As, A, NSUP, rowA0, k0, wave, lane);
    stage_swz(Bs, B, NSUP, rowB0, k0, wave, lane);
    __syncthreads();
    #pragma unroll
    for (int ks = 0; ks < 2; ks++) {
      bhalf8 af[4], bfr[4];
      #pragma unroll
      for (int m = 0; m < 4; m++)
        af[m] = frag_ld(As, wr + m * 16 + lr, ks * 4 + lg, sx);
      #pragma unroll
      for (int n = 0; n < 4; n++)
        bfr[n] = frag_ld(Bs, wc + n * 16 + lr, ks * 4 + lg, sx);
      #pragma unroll
      for (int m = 0; m < 4; m++)
        #pragma unroll
        for (int n = 0; n < 4; n++)
          acc[m][n] = __builtin_amdgcn_mfma_f32_16x16x32_bf16(af[m], bfr[n], acc[m][n], 0, 0, 0);
    }
    __syncthreads();
  }

  #pragma unroll
  for (int m = 0; m < 4; m++)
    #pragma unroll
    for (int n = 0; n < 4; n++)
      #pragma unroll
      for (int r = 0; r < 4; r++) {
        int row = rowA0 + wr + m * 16 + lg * 4 + r;
        int col = rowB0 + wc + n * 16 + lr;
        Cv[(long)row * LDA_A + col] = f2b(acc[m][n][r]);
      }
}

// ---------------------------------------------------------------------------
// Build permuted weights. Permuted col c: unit = (c>>6)*16 + (c&15),
// gate = (c>>4)&3, source row srow = gate*512 + unit.
// We (even window [h|r|q]): [Whh | Wih]; Wo (odd [r|q|h]): [Whh_r | Wih | Whh_h]
// Wq (step0, K=256): Wih only. Plus biasp, S hi/lo, S^T.
// ---------------------------------------------------------------------------
__global__ __launch_bounds__(256) void k_build(
    const float* __restrict__ Wih, const float* __restrict__ Whh,
    const float* __restrict__ bih, const float* __restrict__ bhh,
    const float* __restrict__ S,
    ushort* __restrict__ We, ushort* __restrict__ Wo, ushort* __restrict__ Wq,
    float4* __restrict__ biasp,
    ushort* __restrict__ Shi, ushort* __restrict__ Slo,
    ushort* __restrict__ STb)
{
  int t = blockIdx.x * 256 + threadIdx.x;
  if (t < GATESN * 768) {
    int c = t / 768, k = t % 768;
    int unit = (c >> 6) * 16 + (c & 15);
    int gate = (c >> 4) & 3;
    long srow = (long)(gate * HSZ + unit);
    float ve = (k < HSZ) ? Whh[srow * HSZ + k] : Wih[srow * D_IN + (k - HSZ)];
    float vo;
    if (k < D_IN)      vo = Whh[srow * HSZ + D_IN + k];     // r part
    else if (k < HSZ)  vo = Wih[srow * D_IN + (k - D_IN)];  // q part
    else               vo = Whh[srow * HSZ + (k - HSZ)];    // h part
    We[(long)c * 768 + k] = f2b(ve);
    Wo[(long)c * 768 + k] = f2b(vo);
    if (k < D_IN) Wq[(long)c * D_IN + k] = f2b(Wih[srow * D_IN + k]);
  }
  if (t < HSZ) {
    biasp[t] = make_float4(bih[t] + bhh[t],
                           bih[HSZ + t] + bhh[HSZ + t],
                           bih[2 * HSZ + t] + bhh[2 * HSZ + t],
                           bih[3 * HSZ + t] + bhh[3 * HSZ + t]);
  }
  if (t < NSUP * D_IN) {
    float v = S[t];
    ushort hv = f2b(v);
    Shi[t] = hv;
    Slo[t] = f2b(v - b2f(hv));
    int s = t >> 8, d = t & 255;
    STb[(long)d * NSUP + s] = hv;
  }
}

// q bf16 into A_cat cols 512:768. (h/r slots are fully written before use.)
__global__ __launch_bounds__(256) void k_initA(
    const float* __restrict__ query, ushort* __restrict__ Abuf)
{
  long t = (long)blockIdx.x * 256 + threadIdx.x;   // over BATCH_N*D_IN
  int b = (int)(t >> 8), d = (int)(t & 255);
  Abuf[(long)b * LDA_A + 512 + d] = f2b(query[t]);
}

// Row softmax over 512 cols, fp32 in, bf16 out. 1 wave / row.
__global__ __launch_bounds__(256) void k_softmax(
    const float* __restrict__ sc, ushort* __restrict__ attn)
{
  int row  = blockIdx.x * 4 + (threadIdx.x >> 6);
  int lane = threadIdx.x & 63;
  const float4* sp = reinterpret_cast<const float4*>(sc + (long)row * NSUP);
  float4 v0 = sp[lane];
  float4 v1 = sp[64 + lane];
  float m = fmaxf(fmaxf(fmaxf(v0.x, v0.y), fmaxf(v0.z, v0.w)),
                  fmaxf(fmaxf(v1.x, v1.y), fmaxf(v1.z, v1.w)));
  #pragma unroll
  for (int off = 32; off >= 1; off >>= 1) m = fmaxf(m, __shfl_xor(m, off));
  float e0 = __expf(v0.x - m), e1 = __expf(v0.y - m), e2 = __expf(v0.z - m), e3 = __expf(v0.w - m);
  float e4 = __expf(v1.x - m), e5 = __expf(v1.y - m), e6 = __expf(v1.z - m), e7 = __expf(v1.w - m);
  float s = e0 + e1 + e2 + e3 + e4 + e5 + e6 + e7;
  #pragma unroll
  for (int off = 32; off >= 1; off >>= 1) s += __shfl_xor(s, off);
  float inv = 1.0f / s;
  uint2 p0, p1;
  p0.x = (uint)f2b(e0 * inv) | ((uint)f2b(e1 * inv) << 16);
  p0.y = (uint)f2b(e2 * inv) | ((uint)f2b(e3 * inv) << 16);
  p1.x = (uint)f2b(e4 * inv) | ((uint)f2b(e5 * inv) << 16);
  p1.y = (uint)f2b(e6 * inv) | ((uint)f2b(e7 * inv) << 16);
  uint2* ap = reinterpret_cast<uint2*>(attn + (long)row * NSUP);
  ap[lane] = p0;
  ap[64 + lane] = p1;
}

// ---------------------------------------------------------------------------
extern "C" void kernel_launch(void* const* d_in, const int* in_sizes, int n_in,
                              void* d_out, int out_size, void* d_ws, size_t ws_size,
                              hipStream_t stream)
{
  const float* support_mean = (const float*)d_in[0];
  const float* query_mean   = (const float*)d_in[2];
  const float* W_ih = (const float*)d_in[4];
  const float* W_hh = (const float*)d_in[5];
  const float* b_ih = (const float*)d_in[6];
  const float* b_hh = (const float*)d_in[7];
  float* out = (float*)d_out;

  char* ws = (char*)d_ws;
  size_t off = 0;
  auto alloc = [&](size_t bytes) {
    void* p = ws + off;
    off += (bytes + 255) & ~(size_t)255;
    return p;
  };
  ushort* Abuf  = (ushort*)alloc((size_t)BATCH_N * LDA_A * 2);  // 67.1 MB
  ushort* We    = (ushort*)alloc((size_t)GATESN * 768 * 2);     // 3.1 MB
  ushort* Wo    = (ushort*)alloc((size_t)GATESN * 768 * 2);     // 3.1 MB
  ushort* Wq    = (ushort*)alloc((size_t)GATESN * D_IN * 2);    // 1.05 MB
  float4* biasp = (float4*)alloc((size_t)HSZ * 16);
  ushort* Shi   = (ushort*)alloc((size_t)NSUP * D_IN * 2);
  ushort* Slo   = (ushort*)alloc((size_t)NSUP * D_IN * 2);
  ushort* STb   = (ushort*)alloc((size_t)D_IN * NSUP * 2);
  float*  cbuf  = (float*) alloc((size_t)BATCH_N * HSZ * 4);    // 67.1 MB
  ushort* Hlo   = (ushort*)alloc((size_t)BATCH_N * D_IN * 2);   // 16.8 MB
  ushort* attn  = (ushort*)alloc((size_t)BATCH_N * NSUP * 2);   // 33.6 MB
  if (off > ws_size) return;  // total ~193 MB; >=255 MB proven available

  hipLaunchKernelGGL(k_build, dim3((GATESN * 768) / 256), dim3(256), 0, stream,
                     W_ih, W_hh, b_ih, b_hh, support_mean,
                     We, Wo, Wq, biasp, Shi, Slo, STb);
  hipLaunchKernelGGL(k_initA, dim3((BATCH_N * D_IN) / 256), dim3(256), 0, stream,
                     query_mean, Abuf);

  // step 0: h_r = 0 => gates = q @ Wih^T + b. K=256, no c-read. h -> h_a slot.
  hipLaunchKernelGGL((gemm_gates_fused<1, 256>),
                     dim3((BATCH_N / 128) * (GATESN / 128)), dim3(256), 0, stream,
                     Abuf + 512, Wq, biasp, cbuf, query_mean, Abuf + 0, Hlo);

  for (int s = 0; s < 4; s++) {
    const int hout = (s & 1) * 768;   // where this step's h was written
    // scores = h @ S^T (split precision) -> d_out fp32
    hipLaunchKernelGGL(gemm_scores,
                       dim3((BATCH_N / 128) * (NSUP / 128)), dim3(256), 0, stream,
                       Abuf + hout, LDA_A, Hlo, Shi, Slo, out);
    if (s < 3) {
      hipLaunchKernelGGL(k_softmax, dim3(BATCH_N / 4), dim3(256), 0, stream, out, attn);
      hipLaunchKernelGGL(gemm_pv,
                         dim3((BATCH_N / 128) * (D_IN / 128)), dim3(256), 0, stream,
                         attn, STb, Abuf + 256);
      // next gates step (s+1): window/weights alternate; writes other h slot
      const int aoff  = ((s + 1) == 2) ? 256 : 0;      // 2 -> [r|q|h_b], else [h_a|r|q]
      const ushort* Wnext = ((s + 1) == 2) ? Wo : We;
      hipLaunchKernelGGL((gemm_gates_fused<0, 768>),
                         dim3((BATCH_N / 128) * (GATESN / 128)), dim3(256), 0, stream,
                         Abuf + aoff, Wnext, biasp, cbuf, query_mean,
                         Abuf + ((s + 1) & 1) * 768, Hlo);
    }
  }
}

// Round 6
// 611.150 us; speedup vs baseline: 2.1726x; 1.5789x over previous
//
#include <hip/hip_runtime.h>

typedef unsigned int uint;
typedef unsigned short ushort;
typedef __attribute__((ext_vector_type(8))) short bhalf8;
typedef __attribute__((ext_vector_type(4))) float floatx4;

#define D_IN 256
#define NUNIT 256     // live hidden units (256:512 are dead: h_new[:,256:] never read)
#define GN 1024       // gates N = 4 gates x 256 units
#define NSUP 512
#define BATCH_N 32768
#define LDA_A 768     // A_cat: [h_a(0:256) | r(256:512) | h_b(512:768)]

__device__ __forceinline__ ushort f2b(float f){
  union { float f; uint u; } x; x.f = f;
  uint r = (x.u + 0x7fffu + ((x.u >> 16) & 1u)) >> 16;
  return (ushort)r;
}
__device__ __forceinline__ float b2f(ushort u){
  union { uint u; float f; } x; x.u = ((uint)u) << 16;
  return x.f;
}
__device__ __forceinline__ float sigmf(float x){ return 1.0f / (1.0f + __expf(-x)); }
__device__ __forceinline__ float tanhfast(float x){ return 1.0f - 2.0f / (1.0f + __expf(2.0f * x)); }

// ---------------------------------------------------------------------------
// global->LDS staging of a 128x64 bf16 tile with SOURCE PRE-SWIZZLE (m173):
// LDS linear; lane fetches global octet (lane&7)^(lane>>3) so
// LDS[R][o] = G[R][o ^ (R&7)]; reads apply the same XOR (frag_ld).
// Verified round 5: bank conflicts 3.8e7 -> 0.
// ---------------------------------------------------------------------------
__device__ __forceinline__ void stage_swz(
    ushort* lds, const ushort* __restrict__ g, int ld, int row0, int k0,
    int wave, int lane)
{
  const int rsub = lane >> 3;
  const int oct  = (lane & 7) ^ rsub;
  #pragma unroll
  for (int q = 0; q < 4; q++) {
    const ushort* gp = g + (long)(row0 + wave * 32 + q * 8 + rsub) * ld
                         + k0 + (oct << 3);
    ushort* lp = lds + (wave * 32 + q * 8) * 64;
    __builtin_amdgcn_global_load_lds(
        (const __attribute__((address_space(1))) void*)gp,
        (__attribute__((address_space(3))) void*)lp, 16, 0, 0);
  }
}

__device__ __forceinline__ bhalf8 frag_ld(const ushort* lds, int R, int O, int sx)
{
  return *reinterpret_cast<const bhalf8*>(&lds[R * 64 + (((O ^ sx) & 7) << 3)]);
}

// ---------------------------------------------------------------------------
// Gq = q @ Wq^T + bias (K=256, N=1024, permuted cols), stored packed bf16
// uint2 per (row,unit) = {i|f<<16, g|o<<16}. Epilogue ALSO runs step-0's
// LSTM pointwise (c = i*g ; h = q + o*tanh(c)) -> h_a slot + Hlo.
// ---------------------------------------------------------------------------
__global__ __launch_bounds__(256) void gemm_gq_fused(
    const ushort* __restrict__ Qb,     // [32768,256] bf16
    const ushort* __restrict__ Wq,     // permuted [1024,256]
    const float4* __restrict__ biasp,  // [256] (b_i,b_f,b_g,b_o)
    uint2* __restrict__ Gq,            // [32768*256]
    float* __restrict__ cbuf,          // [32768,256]
    const float* __restrict__ query,   // fp32
    ushort* __restrict__ Hhi,          // Abuf + 0 (stride LDA_A)
    ushort* __restrict__ Hlo)          // [32768,256]
{
  __shared__ ushort As[128 * 64];
  __shared__ ushort Bs[128 * 64];

  const int tid  = threadIdx.x;
  const int lane = tid & 63;
  const int wave = tid >> 6;
  const int wr = (wave >> 1) * 64;
  const int wc = (wave & 1) * 64;
  const int wg = (blockIdx.x & 7) * (gridDim.x >> 3) + (blockIdx.x >> 3);
  const int bm = wg >> 3;             // GN/128 = 8 col-blocks
  const int bn = wg & 7;
  const int rowA0 = bm * 128;
  const int colB0 = bn * 128;

  floatx4 acc[4][4];
  #pragma unroll
  for (int m = 0; m < 4; m++)
    #pragma unroll
    for (int n = 0; n < 4; n++)
      acc[m][n] = (floatx4){0.f, 0.f, 0.f, 0.f};

  const int lr = lane & 15;
  const int lg = lane >> 4;
  const int sx = lane & 7;

  for (int k0 = 0; k0 < 256; k0 += 64) {
    stage_swz(As, Qb, 256, rowA0, k0, wave, lane);
    stage_swz(Bs, Wq, 256, colB0, k0, wave, lane);
    __syncthreads();
    #pragma unroll
    for (int ks = 0; ks < 2; ks++) {
      bhalf8 af[4], bfr[4];
      #pragma unroll
      for (int m = 0; m < 4; m++)
        af[m] = frag_ld(As, wr + m * 16 + lr, ks * 4 + lg, sx);
      #pragma unroll
      for (int n = 0; n < 4; n++)
        bfr[n] = frag_ld(Bs, wc + n * 16 + lr, ks * 4 + lg, sx);
      #pragma unroll
      for (int m = 0; m < 4; m++)
        #pragma unroll
        for (int n = 0; n < 4; n++)
          acc[m][n] = __builtin_amdgcn_mfma_f32_16x16x32_bf16(af[m], bfr[n], acc[m][n], 0, 0, 0);
    }
    __syncthreads();
  }

  const int u = (2 * bn + (wave & 1)) * 16 + lr;   // unit 0..255
  const float4 b4 = biasp[u];
  #pragma unroll
  for (int m = 0; m < 4; m++) {
    #pragma unroll
    for (int rr = 0; rr < 4; rr++) {
      const long row = rowA0 + wr + m * 16 + lg * 4 + rr;
      float pi = acc[m][0][rr] + b4.x;
      float pf = acc[m][1][rr] + b4.y;
      float pg = acc[m][2][rr] + b4.z;
      float po = acc[m][3][rr] + b4.w;
      uint2 pk;
      pk.x = (uint)f2b(pi) | ((uint)f2b(pf) << 16);
      pk.y = (uint)f2b(pg) | ((uint)f2b(po) << 16);
      Gq[row * NUNIT + u] = pk;
      // step-0 pointwise (h_r = 0): c = i*g ; h = q + o*tanh(c)
      float cn = sigmf(pi) * tanhfast(pg);
      cbuf[row * NUNIT + u] = cn;
      float h = query[row * D_IN + u] + sigmf(po) * tanhfast(cn);
      ushort hh = f2b(h);
      Hhi[row * LDA_A + u] = hh;
      Hlo[row * D_IN + u] = f2b(h - b2f(hh));
    }
  }
}

// ---------------------------------------------------------------------------
// Steps 1-3: gates = A[:, aoff:aoff+512] @ Whh'^T (K=512, N=1024) + Gq;
// fused LSTM pointwise epilogue.
// ---------------------------------------------------------------------------
__global__ __launch_bounds__(256) void gemm_gates_fused(
    const ushort* __restrict__ A,      // Abuf + aoff (lda LDA_A)
    const ushort* __restrict__ W,      // permuted [1024,512]
    const uint2* __restrict__ Gq,      // packed q-contribution (incl bias)
    float* __restrict__ cbuf,
    const float* __restrict__ query,
    ushort* __restrict__ Hhi,          // A_cat h-out slot (stride LDA_A)
    ushort* __restrict__ Hlo)
{
  __shared__ ushort As[128 * 64];
  __shared__ ushort Bs[128 * 64];

  const int tid  = threadIdx.x;
  const int lane = tid & 63;
  const int wave = tid >> 6;
  const int wr = (wave >> 1) * 64;
  const int wc = (wave & 1) * 64;
  const int wg = (blockIdx.x & 7) * (gridDim.x >> 3) + (blockIdx.x >> 3);
  const int bm = wg >> 3;             // 8 col-blocks
  const int bn = wg & 7;
  const int rowA0 = bm * 128;
  const int colB0 = bn * 128;

  floatx4 acc[4][4];
  #pragma unroll
  for (int m = 0; m < 4; m++)
    #pragma unroll
    for (int n = 0; n < 4; n++)
      acc[m][n] = (floatx4){0.f, 0.f, 0.f, 0.f};

  const int lr = lane & 15;
  const int lg = lane >> 4;
  const int sx = lane & 7;

  for (int k0 = 0; k0 < 512; k0 += 64) {
    stage_swz(As, A, LDA_A, rowA0, k0, wave, lane);
    stage_swz(Bs, W, 512,   colB0, k0, wave, lane);
    __syncthreads();
    #pragma unroll
    for (int ks = 0; ks < 2; ks++) {
      bhalf8 af[4], bfr[4];
      #pragma unroll
      for (int m = 0; m < 4; m++)
        af[m] = frag_ld(As, wr + m * 16 + lr, ks * 4 + lg, sx);
      #pragma unroll
      for (int n = 0; n < 4; n++)
        bfr[n] = frag_ld(Bs, wc + n * 16 + lr, ks * 4 + lg, sx);
      #pragma unroll
      for (int m = 0; m < 4; m++)
        #pragma unroll
        for (int n = 0; n < 4; n++)
          acc[m][n] = __builtin_amdgcn_mfma_f32_16x16x32_bf16(af[m], bfr[n], acc[m][n], 0, 0, 0);
    }
    __syncthreads();
  }

  const int u = (2 * bn + (wave & 1)) * 16 + lr;
  #pragma unroll
  for (int m = 0; m < 4; m++) {
    #pragma unroll
    for (int rr = 0; rr < 4; rr++) {
      const long row = rowA0 + wr + m * 16 + lg * 4 + rr;
      uint2 pk = Gq[row * NUNIT + u];
      float pi = acc[m][0][rr] + b2f((ushort)(pk.x & 0xffff));
      float pf = acc[m][1][rr] + b2f((ushort)(pk.x >> 16));
      float pg = acc[m][2][rr] + b2f((ushort)(pk.y & 0xffff));
      float po = acc[m][3][rr] + b2f((ushort)(pk.y >> 16));
      float* cp = cbuf + row * NUNIT + u;
      float cn = sigmf(pf) * (*cp) + sigmf(pi) * tanhfast(pg);
      *cp = cn;
      float h = query[row * D_IN + u] + sigmf(po) * tanhfast(cn);
      ushort hh = f2b(h);
      Hhi[row * LDA_A + u] = hh;
      Hlo[row * D_IN + u] = f2b(h - b2f(hh));
    }
  }
}

// ---------------------------------------------------------------------------
// Split-precision scores GEMM: C = (Ahi+Alo)@(Bhi+Blo)^T, lo*lo dropped.
// Ahi from A_cat h-slot (lda 768). K=256. C fp32 [32768,512].
// ---------------------------------------------------------------------------
__global__ __launch_bounds__(256) void gemm_scores(
    const ushort* __restrict__ Ahi,
    const ushort* __restrict__ Alo,
    const ushort* __restrict__ Bhi, const ushort* __restrict__ Blo,
    float* __restrict__ C)
{
  __shared__ ushort AsH[128 * 64];
  __shared__ ushort AsL[128 * 64];
  __shared__ ushort BsH[128 * 64];
  __shared__ ushort BsL[128 * 64];

  const int tid  = threadIdx.x;
  const int lane = tid & 63;
  const int wave = tid >> 6;
  const int wr = (wave >> 1) * 64;
  const int wc = (wave & 1) * 64;
  const int wg = (blockIdx.x & 7) * (gridDim.x >> 3) + (blockIdx.x >> 3);
  const int bm = wg >> 2;      // NSUP/128 = 4
  const int bn = wg & 3;
  const int rowA0 = bm * 128;
  const int rowB0 = bn * 128;

  floatx4 acc[4][4];
  #pragma unroll
  for (int m = 0; m < 4; m++)
    #pragma unroll
    for (int n = 0; n < 4; n++)
      acc[m][n] = (floatx4){0.f, 0.f, 0.f, 0.f};

  const int lr = lane & 15;
  const int lg = lane >> 4;
  const int sx = lane & 7;

  for (int k0 = 0; k0 < D_IN; k0 += 64) {
    stage_swz(AsH, Ahi, LDA_A, rowA0, k0, wave, lane);
    stage_swz(AsL, Alo, D_IN,  rowA0, k0, wave, lane);
    stage_swz(BsH, Bhi, D_IN,  rowB0, k0, wave, lane);
    stage_swz(BsL, Blo, D_IN,  rowB0, k0, wave, lane);
    __syncthreads();
    #pragma unroll
    for (int ks = 0; ks < 2; ks++) {
      bhalf8 afh[4], afl[4], bfh[4], bfl[4];
      #pragma unroll
      for (int m = 0; m < 4; m++) {
        afh[m] = frag_ld(AsH, wr + m * 16 + lr, ks * 4 + lg, sx);
        afl[m] = frag_ld(AsL, wr + m * 16 + lr, ks * 4 + lg, sx);
      }
      #pragma unroll
      for (int n = 0; n < 4; n++) {
        bfh[n] = frag_ld(BsH, wc + n * 16 + lr, ks * 4 + lg, sx);
        bfl[n] = frag_ld(BsL, wc + n * 16 + lr, ks * 4 + lg, sx);
      }
      #pragma unroll
      for (int m = 0; m < 4; m++)
        #pragma unroll
        for (int n = 0; n < 4; n++) {
          acc[m][n] = __builtin_amdgcn_mfma_f32_16x16x32_bf16(afl[m], bfh[n], acc[m][n], 0, 0, 0);
          acc[m][n] = __builtin_amdgcn_mfma_f32_16x16x32_bf16(afh[m], bfl[n], acc[m][n], 0, 0, 0);
          acc[m][n] = __builtin_amdgcn_mfma_f32_16x16x32_bf16(afh[m], bfh[n], acc[m][n], 0, 0, 0);
        }
    }
    __syncthreads();
  }

  #pragma unroll
  for (int m = 0; m < 4; m++)
    #pragma unroll
    for (int n = 0; n < 4; n++)
      #pragma unroll
      for (int r = 0; r < 4; r++) {
        int row = rowA0 + wr + m * 16 + lg * 4 + r;
        int col = rowB0 + wc + n * 16 + lr;
        C[(long)row * NSUP + col] = acc[m][n][r];
      }
}

// ---------------------------------------------------------------------------
// PV GEMM: r = attn @ STb^T (K=512), bf16 out into A_cat r-slot (ldc 768).
// ---------------------------------------------------------------------------
__global__ __launch_bounds__(256) void gemm_pv(
    const ushort* __restrict__ A,      // attn [32768,512]
    const ushort* __restrict__ B,      // STb [256,512]
    ushort* __restrict__ Cv)           // Abuf + 256
{
  __shared__ ushort As[128 * 64];
  __shared__ ushort Bs[128 * 64];

  const int tid  = threadIdx.x;
  const int lane = tid & 63;
  const int wave = tid >> 6;
  const int wr = (wave >> 1) * 64;
  const int wc = (wave & 1) * 64;
  const int wg = (blockIdx.x & 7) * (gridDim.x >> 3) + (blockIdx.x >> 3);
  const int bm = wg >> 1;             // D_IN/128 = 2
  const int bn = wg & 1;
  const int rowA0 = bm * 128;
  const int rowB0 = bn * 128;

  floatx4 acc[4][4];
  #pragma unroll
  for (int m = 0; m < 4; m++)
    #pragma unroll
    for (int n = 0; n < 4; n++)
      acc[m][n] = (floatx4){0.f, 0.f, 0.f, 0.f};

  const int lr = lane & 15;
  const int lg = lane >> 4;
  const int sx = lane & 7;

  for (int k0 = 0; k0 < NSUP; k0 += 64) {
    stage_swz(As, A, NSUP, rowA0, k0, wave, lane);
    stage_swz(Bs, B, NSUP, rowB0, k0, wave, lane);
    __syncthreads();
    #pragma unroll
    for (int ks = 0; ks < 2; ks++) {
      bhalf8 af[4], bfr[4];
      #pragma unroll
      for (int m = 0; m < 4; m++)
        af[m] = frag_ld(As, wr + m * 16 + lr, ks * 4 + lg, sx);
      #pragma unroll
      for (int n = 0; n < 4; n++)
        bfr[n] = frag_ld(Bs, wc + n * 16 + lr, ks * 4 + lg, sx);
      #pragma unroll
      for (int m = 0; m < 4; m++)
        #pragma unroll
        for (int n = 0; n < 4; n++)
          acc[m][n] = __builtin_amdgcn_mfma_f32_16x16x32_bf16(af[m], bfr[n], acc[m][n], 0, 0, 0);
    }
    __syncthreads();
  }

  #pragma unroll
  for (int m = 0; m < 4; m++)
    #pragma unroll
    for (int n = 0; n < 4; n++)
      #pragma unroll
      for (int r = 0; r < 4; r++) {
        int row = rowA0 + wr + m * 16 + lg * 4 + r;
        int col = rowB0 + wc + n * 16 + lr;
        Cv[(long)row * LDA_A + col] = f2b(acc[m][n][r]);
      }
}

// ---------------------------------------------------------------------------
// Build permuted live-unit weights + bias + S hi/lo + S^T.
// Permuted col c (0:1024): unit = (c>>6)*16 + (c&15) in 0:256, gate = (c>>4)&3,
// source row srow = gate*512 + unit.
// We ([h|r] window): Whh cols direct. Wo ([r|h]): swap halves. Wq: Wih.
// ---------------------------------------------------------------------------
__global__ __launch_bounds__(256) void k_build(
    const float* __restrict__ Wih, const float* __restrict__ Whh,
    const float* __restrict__ bih, const float* __restrict__ bhh,
    const float* __restrict__ S,
    ushort* __restrict__ We, ushort* __restrict__ Wo, ushort* __restrict__ Wq,
    float4* __restrict__ biasp,
    ushort* __restrict__ Shi, ushort* __restrict__ Slo,
    ushort* __restrict__ STb)
{
  int t = blockIdx.x * 256 + threadIdx.x;
  if (t < GN * 512) {
    int c = t >> 9, k = t & 511;
    int unit = (c >> 6) * 16 + (c & 15);
    int gate = (c >> 4) & 3;
    long srow = (long)(gate * 512 + unit);
    We[(long)c * 512 + k] = f2b(Whh[srow * 512 + k]);
    int ko = (k < 256) ? (256 + k) : (k - 256);
    Wo[(long)c * 512 + k] = f2b(Whh[srow * 512 + ko]);
    if (k < 256) Wq[(long)c * 256 + k] = f2b(Wih[srow * 256 + k]);
  }
  if (t < NUNIT) {
    biasp[t] = make_float4(bih[t] + bhh[t],
                           bih[512 + t] + bhh[512 + t],
                           bih[1024 + t] + bhh[1024 + t],
                           bih[1536 + t] + bhh[1536 + t]);
  }
  if (t < NSUP * D_IN) {
    float v = S[t];
    ushort hv = f2b(v);
    Shi[t] = hv;
    Slo[t] = f2b(v - b2f(hv));
    int s = t >> 8, d = t & 255;
    STb[(long)d * NSUP + s] = hv;
  }
}

// bf16 copy of query for the Gq GEMM.
__global__ __launch_bounds__(256) void k_initq(
    const float* __restrict__ query, ushort* __restrict__ Qb)
{
  long t = (long)blockIdx.x * 256 + threadIdx.x;
  Qb[t] = f2b(query[t]);
}

// Row softmax over 512 cols, fp32 in, bf16 out. 1 wave / row.
__global__ __launch_bounds__(256) void k_softmax(
    const float* __restrict__ sc, ushort* __restrict__ attn)
{
  int row  = blockIdx.x * 4 + (threadIdx.x >> 6);
  int lane = threadIdx.x & 63;
  const float4* sp = reinterpret_cast<const float4*>(sc + (long)row * NSUP);
  float4 v0 = sp[lane];
  float4 v1 = sp[64 + lane];
  float m = fmaxf(fmaxf(fmaxf(v0.x, v0.y), fmaxf(v0.z, v0.w)),
                  fmaxf(fmaxf(v1.x, v1.y), fmaxf(v1.z, v1.w)));
  #pragma unroll
  for (int off = 32; off >= 1; off >>= 1) m = fmaxf(m, __shfl_xor(m, off));
  float e0 = __expf(v0.x - m), e1 = __expf(v0.y - m), e2 = __expf(v0.z - m), e3 = __expf(v0.w - m);
  float e4 = __expf(v1.x - m), e5 = __expf(v1.y - m), e6 = __expf(v1.z - m), e7 = __expf(v1.w - m);
  float s = e0 + e1 + e2 + e3 + e4 + e5 + e6 + e7;
  #pragma unroll
  for (int off = 32; off >= 1; off >>= 1) s += __shfl_xor(s, off);
  float inv = 1.0f / s;
  uint2 p0, p1;
  p0.x = (uint)f2b(e0 * inv) | ((uint)f2b(e1 * inv) << 16);
  p0.y = (uint)f2b(e2 * inv) | ((uint)f2b(e3 * inv) << 16);
  p1.x = (uint)f2b(e4 * inv) | ((uint)f2b(e5 * inv) << 16);
  p1.y = (uint)f2b(e6 * inv) | ((uint)f2b(e7 * inv) << 16);
  uint2* ap = reinterpret_cast<uint2*>(attn + (long)row * NSUP);
  ap[lane] = p0;
  ap[64 + lane] = p1;
}

// ---------------------------------------------------------------------------
extern "C" void kernel_launch(void* const* d_in, const int* in_sizes, int n_in,
                              void* d_out, int out_size, void* d_ws, size_t ws_size,
                              hipStream_t stream)
{
  const float* support_mean = (const float*)d_in[0];
  const float* query_mean   = (const float*)d_in[2];
  const float* W_ih = (const float*)d_in[4];
  const float* W_hh = (const float*)d_in[5];
  const float* b_ih = (const float*)d_in[6];
  const float* b_hh = (const float*)d_in[7];
  float* out = (float*)d_out;

  char* ws = (char*)d_ws;
  size_t off = 0;
  auto alloc = [&](size_t bytes) {
    void* p = ws + off;
    off += (bytes + 255) & ~(size_t)255;
    return p;
  };
  ushort* Abuf  = (ushort*)alloc((size_t)BATCH_N * LDA_A * 2);  // 50.3 MB
  ushort* Qb    = (ushort*)alloc((size_t)BATCH_N * D_IN * 2);   // 16.8 MB
  ushort* We    = (ushort*)alloc((size_t)GN * 512 * 2);         // 1.05 MB
  ushort* Wo    = (ushort*)alloc((size_t)GN * 512 * 2);         // 1.05 MB
  ushort* Wq    = (ushort*)alloc((size_t)GN * 256 * 2);         // 0.52 MB
  float4* biasp = (float4*)alloc((size_t)NUNIT * 16);
  ushort* Shi   = (ushort*)alloc((size_t)NSUP * D_IN * 2);
  ushort* Slo   = (ushort*)alloc((size_t)NSUP * D_IN * 2);
  ushort* STb   = (ushort*)alloc((size_t)D_IN * NSUP * 2);
  float*  cbuf  = (float*) alloc((size_t)BATCH_N * NUNIT * 4);  // 33.6 MB
  ushort* Hlo   = (ushort*)alloc((size_t)BATCH_N * D_IN * 2);   // 16.8 MB
  uint2*  Gq    = (uint2*) alloc((size_t)BATCH_N * NUNIT * 8);  // 67.1 MB
  ushort* attn  = (ushort*)alloc((size_t)BATCH_N * NSUP * 2);   // 33.6 MB
  if (off > ws_size) return;  // total ~222 MB; >=255 MB proven available

  hipLaunchKernelGGL(k_build, dim3((GN * 512) / 256), dim3(256), 0, stream,
                     W_ih, W_hh, b_ih, b_hh, support_mean,
                     We, Wo, Wq, biasp, Shi, Slo, STb);
  hipLaunchKernelGGL(k_initq, dim3((BATCH_N * D_IN) / 256), dim3(256), 0, stream,
                     query_mean, Qb);

  // Gq = q@Wq^T + b (shared by all steps) + step-0 pointwise -> h_a, c.
  hipLaunchKernelGGL(gemm_gq_fused,
                     dim3((BATCH_N / 128) * (GN / 128)), dim3(256), 0, stream,
                     Qb, Wq, biasp, Gq, cbuf, query_mean, Abuf + 0, Hlo);

  for (int s = 0; s < 4; s++) {
    const int hoff = (s & 1) * 512;   // h slot of step s: even->h_a(0), odd->h_b(512)
    hipLaunchKernelGGL(gemm_scores,
                       dim3((BATCH_N / 128) * (NSUP / 128)), dim3(256), 0, stream,
                       Abuf + hoff, Hlo, Shi, Slo, out);
    if (s < 3) {
      hipLaunchKernelGGL(k_softmax, dim3(BATCH_N / 4), dim3(256), 0, stream, out, attn);
      hipLaunchKernelGGL(gemm_pv,
                         dim3((BATCH_N / 128) * (D_IN / 128)), dim3(256), 0, stream,
                         attn, STb, Abuf + 256);
      // gates for step s+1: window [h|r] (cols 0:512, We) except step 2 reads
      // [r|h_b] (cols 256:768, Wo). h-out goes to the other slot.
      const int aoff = ((s + 1) == 2) ? 256 : 0;
      const ushort* Wnext = ((s + 1) == 2) ? Wo : We;
      hipLaunchKernelGGL(gemm_gates_fused,
                         dim3((BATCH_N / 128) * (GN / 128)), dim3(256), 0, stream,
                         Abuf + aoff, Wnext, Gq, cbuf, query_mean,
                         Abuf + ((s + 1) & 1) * 512, Hlo);
    }
  }
}